// Round 6
// baseline (1535.289 us; speedup 1.0000x reference)
//
#include <hip/hip_runtime.h>
#include <hip/hip_bf16.h>

// Fused linear-projection + cross-entropy, N=8192 D=2048 V=32000.
// R6: barrier-minimal K-loop. Per K-tile: {24 ds_read (compiler-scheduled)
// -> 64 MFMA (drain hides under MFMA) -> lgkmcnt(0) -> barrier ->
// stage t+2 into cur -> vmcnt(8) -> barrier}. 2 barriers/tile (was 8).
// Ledger: 8 outstanding (tile t+1) at tile entry; vmcnt(8) retires it.

typedef __bf16 bf16_t;
typedef bf16_t bf16x8 __attribute__((ext_vector_type(8)));
typedef float f32x4 __attribute__((ext_vector_type(4)));

constexpr int N_TOK = 8192;
constexpr int DIM   = 2048;
constexpr int VOCAB = 32000;
constexpr int BM = 256, BN = 256, BK = 64;
constexpr int MT  = N_TOK / BM;   // 32 row tiles
constexpr int NVT = VOCAB / BN;   // 125 vocab tiles
constexpr int NKT = DIM / BK;     // 32 K tiles
constexpr int IGNORE_INDEX = -100;

#define GPTR(p) ((const __attribute__((address_space(1))) void*)(p))
#define LPTR(p) ((__attribute__((address_space(3))) void*)(p))

#define VMCNT(N)                                            \
  asm volatile("s_waitcnt vmcnt(" #N ")" ::: "memory");     \
  __builtin_amdgcn_sched_barrier(0)
#define LGKM0()                                             \
  asm volatile("s_waitcnt lgkmcnt(0)" ::: "memory");        \
  __builtin_amdgcn_sched_barrier(0)

__device__ __forceinline__ bf16_t f2bf(float f) {
  union { float f; unsigned u; } in; in.f = f;
  unsigned u = in.u;
  unsigned r = u + 0x7fffu + ((u >> 16) & 1u);   // RNE
  union { unsigned short s; bf16_t b; } out;
  out.s = (unsigned short)(r >> 16);
  return out.b;
}

// ---------------- fp32 -> bf16 convert, grid-stride ------------------------
constexpr int XN8 = N_TOK * DIM / 8;   // 2,097,152
constexpr int WN8 = VOCAB * DIM / 8;   // 8,192,000
constexpr int CVT_BLOCKS = 2048;

__global__ __launch_bounds__(256) void cvt_both(const float* __restrict__ x,
                                                const float* __restrict__ w,
                                                bf16_t* __restrict__ xb,
                                                bf16_t* __restrict__ wb) {
  for (int i = blockIdx.x * 256 + threadIdx.x; i < XN8 + WN8; i += CVT_BLOCKS * 256) {
    const float* src; bf16_t* dst; int j;
    if (i < XN8) { src = x; dst = xb; j = i; }
    else { src = w; dst = wb; j = i - XN8; }
    const float4* s = (const float4*)src;
    float4 a = s[2 * (size_t)j], b = s[2 * (size_t)j + 1];
    bf16x8 o;
    o[0] = f2bf(a.x); o[1] = f2bf(a.y); o[2] = f2bf(a.z); o[3] = f2bf(a.w);
    o[4] = f2bf(b.x); o[5] = f2bf(b.y); o[6] = f2bf(b.z); o[7] = f2bf(b.w);
    *(bf16x8*)(dst + (size_t)j * 8) = o;
  }
}

// ---------------- GEMM helpers --------------------------------------------
// LDS slot map (slot in {0,65536}): A-low rows 0..127 @slot, A-high @slot
// +16384, B rows 0..255 @slot+32768. Swizzle: 16B-chunk ^= (row&7) on the
// global source (linear LDS dest) AND on the ds_read address (rule #21).
__device__ __forceinline__ void stage_half(const bf16_t* base, int kt,
                                           long toff, char* smem, int ldsoff,
                                           int tid) {
  const bf16_t* g = base + kt * BK + toff;
  __builtin_amdgcn_global_load_lds(GPTR(g), LPTR(smem + ldsoff + tid * 16), 16, 0, 0);
  __builtin_amdgcn_global_load_lds(GPTR(g + 64 * DIM), LPTR(smem + ldsoff + 8192 + tid * 16), 16, 0, 0);
}

template <int SLOT>
__device__ __forceinline__ bf16x8 ldA(const char* smem, int row, int ks, int lg) {
  int ch = (ks * 4 + lg) ^ (row & 7);
  return *(const bf16x8*)(smem + SLOT + row * 128 + ch * 16);
}
template <int SLOT>
__device__ __forceinline__ bf16x8 ldB(const char* smem, int row, int ks, int lg) {
  int ch = (ks * 4 + lg) ^ (row & 7);
  return *(const bf16x8*)(smem + SLOT + 32768 + row * 128 + ch * 16);
}

// One K-tile, barrier-minimal. CUR = this tile's LDS slot; stages tile t+2
// into CUR after the WAR barrier. No fences inside the read/MFMA region:
// compiler interleaves ds_read drains with MFMAs via fine-grained lgkmcnt.
template <int CUR>
__device__ __forceinline__ void tile_body(
    const bf16_t* Ab, const bf16_t* Bb, int ktN, long toff, char* smem,
    int tid, int arow, int brow, int lg, f32x4 (&acc)[8][4]) {
  bf16x8 a0[8], b0[4], a1[8], b1[4];
#pragma unroll
  for (int m = 0; m < 8; ++m) a0[m] = ldA<CUR>(smem, arow + m * 16, 0, lg);
#pragma unroll
  for (int n = 0; n < 4; ++n) b0[n] = ldB<CUR>(smem, brow + n * 16, 0, lg);
#pragma unroll
  for (int m = 0; m < 8; ++m) a1[m] = ldA<CUR>(smem, arow + m * 16, 1, lg);
#pragma unroll
  for (int n = 0; n < 4; ++n) b1[n] = ldB<CUR>(smem, brow + n * 16, 1, lg);
  __builtin_amdgcn_s_setprio(1);
#pragma unroll
  for (int m = 0; m < 8; ++m)
#pragma unroll
    for (int n = 0; n < 4; ++n)
      acc[m][n] = __builtin_amdgcn_mfma_f32_16x16x32_bf16(a0[m], b0[n], acc[m][n], 0, 0, 0);
#pragma unroll
  for (int m = 0; m < 8; ++m)
#pragma unroll
    for (int n = 0; n < 4; ++n)
      acc[m][n] = __builtin_amdgcn_mfma_f32_16x16x32_bf16(a1[m], b1[n], acc[m][n], 0, 0, 0);
  __builtin_amdgcn_s_setprio(0);
  LGKM0();                          // own LDS reads complete (WAR safety)
  __builtin_amdgcn_s_barrier();     // all waves' reads of CUR complete
  stage_half(Ab,             ktN, toff, smem, CUR,         tid);
  stage_half(Ab + 128 * DIM, ktN, toff, smem, CUR + 16384, tid);
  stage_half(Bb,             ktN, toff, smem, CUR + 32768, tid);
  stage_half(Bb + 128 * DIM, ktN, toff, smem, CUR + 49152, tid);
  VMCNT(8);                         // tile t+1 (issued last iter) resident
  __builtin_amdgcn_s_barrier();     // all waves agree; t+2 stays in flight
}

// ---------------- main: 256^2 barrier-minimal GEMM + fused LSE ------------
__global__ __launch_bounds__(512, 2) void fused_gemm_lse(
    const bf16_t* __restrict__ X, const bf16_t* __restrict__ W,
    const int* __restrict__ target,
    float2* __restrict__ partials, float* __restrict__ tgt_logit) {
  __shared__ __align__(16) char smem[131072];

  const int tid  = threadIdx.x;
  const int lane = tid & 63;
  const int wid  = tid >> 6;
  const int wr   = wid >> 2;   // 2 wave-rows (128 M each)
  const int wc   = wid & 3;    // 4 wave-cols (64 N each)
  const int l15  = lane & 15;
  const int lg   = lane >> 4;
  const int arow = wr * 128 + l15;
  const int brow = wc * 64 + l15;

  // XCD-bijective swizzle (grid 4000 = 8*500); M-fastest: one XCD's 32
  // concurrent blocks share one 1 MB W panel in its L2.
  int bid  = blockIdx.x;
  int wgid = (bid & 7) * (MT * NVT / 8) + (bid >> 3);
  int mt = wgid & (MT - 1);
  int vt = wgid >> 5;
  const int brow_g = mt * BM;
  const int bcol_g = vt * BN;

  const bf16_t* Abase = X + (size_t)brow_g * DIM;
  const bf16_t* Bbase = W + (size_t)bcol_g * DIM;

  // per-thread stage offset (elements): row = tid>>3, chunk = (tid&7)^(row&7)
  const int srow = tid >> 3;
  const int ssc  = (tid & 7) ^ (srow & 7);
  const long toff = (long)srow * DIM + ssc * 8;

  f32x4 acc[8][4];
#pragma unroll
  for (int m = 0; m < 8; ++m)
#pragma unroll
    for (int n = 0; n < 4; ++n)
      acc[m][n] = (f32x4){0.f, 0.f, 0.f, 0.f};

  // prologue: stage tile0 -> slot0, tile1 -> slot1 (16 loads); retire tile0.
  stage_half(Abase,             0, toff, smem, 0,             tid);
  stage_half(Abase + 128 * DIM, 0, toff, smem, 16384,         tid);
  stage_half(Bbase,             0, toff, smem, 32768,         tid);
  stage_half(Bbase + 128 * DIM, 0, toff, smem, 49152,         tid);
  stage_half(Abase,             1, toff, smem, 65536,         tid);
  stage_half(Abase + 128 * DIM, 1, toff, smem, 65536 + 16384, tid);
  stage_half(Bbase,             1, toff, smem, 65536 + 32768, tid);
  stage_half(Bbase + 128 * DIM, 1, toff, smem, 65536 + 49152, tid);
  VMCNT(8);
  __builtin_amdgcn_s_barrier();

  for (int t = 0; t < NKT; t += 2) {
    tile_body<0>(Abase, Bbase, (t + 2) & (NKT - 1), toff, smem, tid, arow, brow, lg, acc);
    tile_body<65536>(Abase, Bbase, (t + 3) & (NKT - 1), toff, smem, tid, arow, brow, lg, acc);
  }

  // ---- fused epilogue: per-row (max,sumexp) over this block's 256 cols ----
  __syncthreads();   // drains in-flight wrap stages, frees LDS
  float* smax = (float*)smem;            // [256][4]
  float* ssum = (float*)(smem + 4096);   // [256][4]
#pragma unroll
  for (int m = 0; m < 8; ++m) {
#pragma unroll
    for (int i = 0; i < 4; ++i) {
      int rloc = wr * 128 + m * 16 + lg * 4 + i;
      int grow = brow_g + rloc;
      int tgt  = target[grow];
      float v0 = acc[m][0][i], v1 = acc[m][1][i], v2 = acc[m][2][i], v3 = acc[m][3][i];
      int colbase = bcol_g + wc * 64 + l15;
      if (colbase      == tgt) tgt_logit[grow] = v0;
      if (colbase + 16 == tgt) tgt_logit[grow] = v1;
      if (colbase + 32 == tgt) tgt_logit[grow] = v2;
      if (colbase + 48 == tgt) tgt_logit[grow] = v3;
      float rmax = fmaxf(fmaxf(v0, v1), fmaxf(v2, v3));
#pragma unroll
      for (int s = 1; s < 16; s <<= 1) rmax = fmaxf(rmax, __shfl_xor(rmax, s));
      float rsum = __expf(v0 - rmax) + __expf(v1 - rmax) +
                   __expf(v2 - rmax) + __expf(v3 - rmax);
#pragma unroll
      for (int s = 1; s < 16; s <<= 1) rsum += __shfl_xor(rsum, s);
      if (l15 == 0) { smax[rloc * 4 + wc] = rmax; ssum[rloc * 4 + wc] = rsum; }
    }
  }
  __syncthreads();
  if (tid < BM) {
    float M = smax[tid * 4], S = ssum[tid * 4];
#pragma unroll
    for (int c = 1; c < 4; ++c) {
      float m2 = smax[tid * 4 + c], s2 = ssum[tid * 4 + c];
      float Mn = fmaxf(M, m2);
      S = S * __expf(M - Mn) + s2 * __expf(m2 - Mn);
      M = Mn;
    }
    partials[(size_t)(brow_g + tid) * NVT + vt] = make_float2(M, S);
  }
}

// ---------------- per-row LSE combine + loss; 4 rows/block -----------------
__global__ __launch_bounds__(256) void finalize_rows(
    const float2* __restrict__ partials, const float* __restrict__ tgt_logit,
    const int* __restrict__ target, float2* __restrict__ blocksum) {
  int tid = threadIdx.x, lane = tid & 63, w = tid >> 6;
  int row = blockIdx.x * 4 + w;
  float M = -1e30f, S = 0.f;
  for (int i = lane; i < NVT; i += 64) {
    float2 p = partials[(size_t)row * NVT + i];
    float Mn = fmaxf(M, p.x);
    S = S * __expf(M - Mn) + p.y * __expf(p.x - Mn);
    M = Mn;
  }
#pragma unroll
  for (int s = 1; s < 64; s <<= 1) {
    float Mo = __shfl_xor(M, s), So = __shfl_xor(S, s);
    float Mn = fmaxf(M, Mo);
    S = S * __expf(M - Mn) + So * __expf(Mo - Mn);
    M = Mn;
  }
  __shared__ float ls[4], cs[4];
  if (lane == 0) {
    int t = target[row];
    bool valid = (t != IGNORE_INDEX);
    float lse = M + __logf(S);
    ls[w] = valid ? (lse - tgt_logit[row]) : 0.f;
    cs[w] = valid ? 1.f : 0.f;
  }
  __syncthreads();
  if (tid == 0)
    blocksum[blockIdx.x] = make_float2(ls[0] + ls[1] + ls[2] + ls[3],
                                       cs[0] + cs[1] + cs[2] + cs[3]);
}

__global__ __launch_bounds__(256) void finalize_out(
    const float2* __restrict__ blocksum, float* __restrict__ out) {
  int tid = threadIdx.x;
  float s = 0.f, c = 0.f;
  for (int i = tid; i < N_TOK / 4; i += 256) {
    float2 b = blocksum[i];
    s += b.x; c += b.y;
  }
#pragma unroll
  for (int k = 1; k < 64; k <<= 1) { s += __shfl_xor(s, k); c += __shfl_xor(c, k); }
  __shared__ float ss[4], cc[4];
  int w = tid >> 6;
  if ((tid & 63) == 0) { ss[w] = s; cc[w] = c; }
  __syncthreads();
  if (tid == 0) out[0] = (ss[0] + ss[1] + ss[2] + ss[3]) / (cc[0] + cc[1] + cc[2] + cc[3]);
}

extern "C" void kernel_launch(void* const* d_in, const int* in_sizes, int n_in,
                              void* d_out, int out_size, void* d_ws, size_t ws_size,
                              hipStream_t stream) {
  const float* x = (const float*)d_in[0];
  const float* w = (const float*)d_in[1];
  const int* target = (const int*)d_in[2];
  float* out = (float*)d_out;

  char* ws = (char*)d_ws;
  size_t off = 0;
  bf16_t* Xbf = (bf16_t*)(ws + off); off += (size_t)N_TOK * DIM * 2;      // 32 MB
  bf16_t* Wbf = (bf16_t*)(ws + off); off += (size_t)VOCAB * DIM * 2;      // 128 MB
  float2* partials = (float2*)(ws + off); off += (size_t)N_TOK * NVT * 8; // 8 MB
  float*  tgtlog   = (float*)(ws + off);  off += (size_t)N_TOK * 4;
  float2* blocksum = (float2*)(ws + off); off += (size_t)(N_TOK / 4) * 8;
  (void)ws_size; (void)in_sizes; (void)n_in; (void)out_size;

  cvt_both<<<CVT_BLOCKS, 256, 0, stream>>>(x, w, Xbf, Wbf);
  fused_gemm_lse<<<MT * NVT, 512, 0, stream>>>(Xbf, Wbf, target, partials, tgtlog);
  finalize_rows<<<N_TOK / 4, 256, 0, stream>>>(partials, tgtlog, target, blocksum);
  finalize_out<<<1, 256, 0, stream>>>(blocksum, out);
}